// Round 1
// baseline (2663.765 us; speedup 1.0000x reference)
//
#include <hip/hip_runtime.h>
#include <math.h>

// Problem constants (match reference)
#define D_MODEL 1024
#define N_HEADS 16
#define DK      64
#define B_SZ    4
#define T_SEQ   2048
// Workspace layout (fp32):
//   qkv : [B, T, 3*D_MODEL]  = 25,165,824 floats (100.7 MB)
//   y   : [B, T, D_MODEL]    =  8,388,608 floats ( 33.5 MB)
// total 134.2 MB — fully rewritten every launch (poison-safe).

// ---------------------------------------------------------------------------
// fp32 tiled GEMM: C[M,N] = A[M,K] @ B[K,N] + bias[N]
// 128x128 tile, BK=8, 256 threads, 8x8 microtile. M,N,K multiples of 128/8.
// ---------------------------------------------------------------------------
__global__ __launch_bounds__(256)
void gemm_bias(const float* __restrict__ A, const float* __restrict__ Bm,
               const float* __restrict__ bias, float* __restrict__ C,
               int M, int N, int K) {
    __shared__ float As[8][128];
    __shared__ float Bs[8][128];
    const int tid = threadIdx.x;
    const int bn  = blockIdx.x * 128;
    const int bm  = blockIdx.y * 128;
    const int tx  = tid & 15;        // 16 col-threads * 8 = 128
    const int ty  = tid >> 4;        // 16 row-threads * 8 = 128

    float acc[8][8];
#pragma unroll
    for (int i = 0; i < 8; ++i)
#pragma unroll
        for (int j = 0; j < 8; ++j) acc[i][j] = 0.f;

    const int ar = tid >> 1;           // A tile row 0..127
    const int ak = (tid & 1) * 4;      // A tile k-offset 0 or 4
    const int br = tid >> 5;           // B tile row 0..7
    const int bc = (tid & 31) * 4;     // B tile col 0..124

    for (int k0 = 0; k0 < K; k0 += 8) {
        float4 av = *reinterpret_cast<const float4*>(&A[(size_t)(bm + ar) * K + k0 + ak]);
        float4 bv = *reinterpret_cast<const float4*>(&Bm[(size_t)(k0 + br) * N + bn + bc]);
        __syncthreads();   // previous iteration's readers are done
        As[ak + 0][ar] = av.x;
        As[ak + 1][ar] = av.y;
        As[ak + 2][ar] = av.z;
        As[ak + 3][ar] = av.w;
        *reinterpret_cast<float4*>(&Bs[br][bc]) = bv;
        __syncthreads();
#pragma unroll
        for (int k = 0; k < 8; ++k) {
            float a[8], b[8];
#pragma unroll
            for (int i = 0; i < 8; ++i) a[i] = As[k][ty * 8 + i];
#pragma unroll
            for (int j = 0; j < 8; ++j) b[j] = Bs[k][tx * 8 + j];
#pragma unroll
            for (int i = 0; i < 8; ++i)
#pragma unroll
                for (int j = 0; j < 8; ++j)
                    acc[i][j] = fmaf(a[i], b[j], acc[i][j]);
        }
    }

#pragma unroll
    for (int i = 0; i < 8; ++i) {
        const int m = bm + ty * 8 + i;
#pragma unroll
        for (int j = 0; j < 8; j += 4) {
            const int n = bn + tx * 8 + j;
            float4 o;
            o.x = acc[i][j + 0] + bias[n + 0];
            o.y = acc[i][j + 1] + bias[n + 1];
            o.z = acc[i][j + 2] + bias[n + 2];
            o.w = acc[i][j + 3] + bias[n + 3];
            *reinterpret_cast<float4*>(&C[(size_t)m * N + n]) = o;
        }
    }
}

// ---------------------------------------------------------------------------
// Flash-style causal attention (fp32).
// Block = 256 threads handles one (b, h, 64-query tile); loops over key tiles
// of 64 up to the diagonal. Online softmax state (m, l) lives in registers,
// replicated across the 16 lanes that own one query row (width-16 shfl_xor).
// LDS: Qs[64][68], KP[64][68] (K^T then P), Vs[64][68]  -> 51 KiB.
// ---------------------------------------------------------------------------
__global__ __launch_bounds__(256)
void attn_causal(const float* __restrict__ qkv, float* __restrict__ y) {
    const int qb = blockIdx.x;                 // query tile 0..31
    const int bh = blockIdx.y;                 // 0..63
    const int b  = bh / N_HEADS;
    const int h  = bh % N_HEADS;
    const int tid = threadIdx.x;
    const int tx  = tid & 15;                  // key/dk columns, 4 each
    const int ty  = tid >> 4;                  // query rows, 4 each

    __shared__ float Qs[64][68];
    __shared__ float KP[64][68];               // K^T (d-major), later P
    __shared__ float Vs[64][68];

    const size_t base = ((size_t)b * T_SEQ) * (3 * D_MODEL) + (size_t)h * DK;

    // Load Q tile [64 rows][64 dk], row-major.
    for (int f = tid; f < 64 * 16; f += 256) {
        const int r = f >> 4, c4 = f & 15;
        float4 v = *reinterpret_cast<const float4*>(
            &qkv[base + (size_t)(qb * 64 + r) * (3 * D_MODEL) + c4 * 4]);
        *reinterpret_cast<float4*>(&Qs[r][c4 * 4]) = v;
    }

    float m[4], l[4], acc[4][4];
#pragma unroll
    for (int i = 0; i < 4; ++i) {
        m[i] = -1e30f; l[i] = 0.f;
#pragma unroll
        for (int j = 0; j < 4; ++j) acc[i][j] = 0.f;
    }
    const float sc_qk = 0.125f;                // 1/sqrt(64)

    for (int kb = 0; kb <= qb; ++kb) {
        __syncthreads();                       // prior PV readers done
        // Load K^T (d-major) and V (row-major) tiles.
        for (int f = tid; f < 64 * 16; f += 256) {
            const int r = f >> 4, c4 = f & 15;
            const size_t krow = base + (size_t)(kb * 64 + r) * (3 * D_MODEL);
            float4 kv = *reinterpret_cast<const float4*>(&qkv[krow + D_MODEL + c4 * 4]);
            float4 vv = *reinterpret_cast<const float4*>(&qkv[krow + 2 * D_MODEL + c4 * 4]);
            KP[c4 * 4 + 0][r] = kv.x;
            KP[c4 * 4 + 1][r] = kv.y;
            KP[c4 * 4 + 2][r] = kv.z;
            KP[c4 * 4 + 3][r] = kv.w;
            *reinterpret_cast<float4*>(&Vs[r][c4 * 4]) = vv;
        }
        __syncthreads();

        // S = Q @ K^T  (each thread: 4 query rows x 4 keys)
        float s[4][4];
#pragma unroll
        for (int i = 0; i < 4; ++i)
#pragma unroll
            for (int j = 0; j < 4; ++j) s[i][j] = 0.f;

#pragma unroll
        for (int d4 = 0; d4 < 16; ++d4) {
            float4 a[4];
            float  bv[4][4];                    // [dd][j]
#pragma unroll
            for (int i = 0; i < 4; ++i)
                a[i] = *reinterpret_cast<const float4*>(&Qs[ty * 4 + i][d4 * 4]);
#pragma unroll
            for (int dd = 0; dd < 4; ++dd) {
                float4 t = *reinterpret_cast<const float4*>(&KP[d4 * 4 + dd][tx * 4]);
                bv[dd][0] = t.x; bv[dd][1] = t.y; bv[dd][2] = t.z; bv[dd][3] = t.w;
            }
#pragma unroll
            for (int i = 0; i < 4; ++i)
#pragma unroll
                for (int j = 0; j < 4; ++j)
                    s[i][j] += a[i].x * bv[0][j] + a[i].y * bv[1][j] +
                               a[i].z * bv[2][j] + a[i].w * bv[3][j];
        }

        // scale + causal mask (only the diagonal tile needs masking)
#pragma unroll
        for (int i = 0; i < 4; ++i)
#pragma unroll
            for (int j = 0; j < 4; ++j) s[i][j] *= sc_qk;
        if (kb == qb) {
#pragma unroll
            for (int i = 0; i < 4; ++i)
#pragma unroll
                for (int j = 0; j < 4; ++j)
                    if (tx * 4 + j > ty * 4 + i) s[i][j] = -1e30f;
        }

        // online softmax per query row (reduce across the 16 tx lanes)
#pragma unroll
        for (int i = 0; i < 4; ++i) {
            float rm = fmaxf(fmaxf(s[i][0], s[i][1]), fmaxf(s[i][2], s[i][3]));
#pragma unroll
            for (int off = 1; off < 16; off <<= 1)
                rm = fmaxf(rm, __shfl_xor(rm, off, 16));
            const float mn = fmaxf(m[i], rm);
            float rs = 0.f;
#pragma unroll
            for (int j = 0; j < 4; ++j) {
                const float p = __expf(s[i][j] - mn);
                s[i][j] = p; rs += p;
            }
#pragma unroll
            for (int off = 1; off < 16; off <<= 1)
                rs += __shfl_xor(rs, off, 16);
            const float scl = __expf(m[i] - mn);
            l[i] = l[i] * scl + rs;
            m[i] = mn;
#pragma unroll
            for (int j = 0; j < 4; ++j) acc[i][j] *= scl;
        }

        __syncthreads();                       // all done reading K^T
        // write P over the K^T buffer
#pragma unroll
        for (int i = 0; i < 4; ++i) {
            float4 p4; p4.x = s[i][0]; p4.y = s[i][1]; p4.z = s[i][2]; p4.w = s[i][3];
            *reinterpret_cast<float4*>(&KP[ty * 4 + i][tx * 4]) = p4;
        }
        __syncthreads();

        // O += P @ V
#pragma unroll
        for (int k4 = 0; k4 < 16; ++k4) {
            float pv[4][4];                    // [i][kk]
            float vv[4][4];                    // [kk][j]
#pragma unroll
            for (int i = 0; i < 4; ++i) {
                float4 t = *reinterpret_cast<const float4*>(&KP[ty * 4 + i][k4 * 4]);
                pv[i][0] = t.x; pv[i][1] = t.y; pv[i][2] = t.z; pv[i][3] = t.w;
            }
#pragma unroll
            for (int kk = 0; kk < 4; ++kk) {
                float4 t = *reinterpret_cast<const float4*>(&Vs[k4 * 4 + kk][tx * 4]);
                vv[kk][0] = t.x; vv[kk][1] = t.y; vv[kk][2] = t.z; vv[kk][3] = t.w;
            }
#pragma unroll
            for (int i = 0; i < 4; ++i)
#pragma unroll
                for (int j = 0; j < 4; ++j)
                    acc[i][j] += pv[i][0] * vv[0][j] + pv[i][1] * vv[1][j] +
                                 pv[i][2] * vv[2][j] + pv[i][3] * vv[3][j];
        }
    }

    // epilogue: y[b, q, h*64 + col] = acc / l
#pragma unroll
    for (int i = 0; i < 4; ++i) {
        const int q = qb * 64 + ty * 4 + i;
        const float inv = 1.f / l[i];
        float4 o;
        o.x = acc[i][0] * inv; o.y = acc[i][1] * inv;
        o.z = acc[i][2] * inv; o.w = acc[i][3] * inv;
        *reinterpret_cast<float4*>(
            &y[((size_t)b * T_SEQ + q) * D_MODEL + (size_t)h * DK + tx * 4]) = o;
    }
}

// ---------------------------------------------------------------------------
extern "C" void kernel_launch(void* const* d_in, const int* in_sizes, int n_in,
                              void* d_out, int out_size, void* d_ws, size_t ws_size,
                              hipStream_t stream) {
    const float* x      = (const float*)d_in[0];   // [B,T,C]
    const float* W_qkv  = (const float*)d_in[1];   // [C,3C]
    const float* b_qkv  = (const float*)d_in[2];   // [3C]
    const float* W_proj = (const float*)d_in[3];   // [C,C]
    const float* b_proj = (const float*)d_in[4];   // [C]
    float* out = (float*)d_out;                    // [B,T,C]

    float* qkv = (float*)d_ws;                                   // [B,T,3C]
    float* y   = qkv + (size_t)B_SZ * T_SEQ * 3 * D_MODEL;       // [B,T,C]

    const int M = B_SZ * T_SEQ;     // 8192

    // 1) qkv = x @ W_qkv + b_qkv       [8192,1024]@[1024,3072]
    gemm_bias<<<dim3(3 * D_MODEL / 128, M / 128), 256, 0, stream>>>(
        x, W_qkv, b_qkv, qkv, M, 3 * D_MODEL, D_MODEL);

    // 2) causal attention -> y [B,T,C]
    attn_causal<<<dim3(T_SEQ / 64, B_SZ * N_HEADS), 256, 0, stream>>>(qkv, y);

    // 3) out = y @ W_proj + b_proj     [8192,1024]@[1024,1024]
    gemm_bias<<<dim3(D_MODEL / 128, M / 128), 256, 0, stream>>>(
        y, W_proj, b_proj, out, M, D_MODEL, D_MODEL);
}

// Round 2
// 1025.011 us; speedup vs baseline: 2.5988x; 2.5988x over previous
//
#include <hip/hip_runtime.h>
#include <math.h>
#include <stdint.h>

#define D_MODEL 1024
#define NH      16
#define DK      64
#define BS      4
#define TS      2048
#define M_ROWS  (BS*TS)       // 8192
#define C3      (3*D_MODEL)   // 3072

typedef __attribute__((ext_vector_type(8))) short          short8;
typedef __attribute__((ext_vector_type(4))) short          short4_t;
typedef __attribute__((ext_vector_type(4))) float          f32x4;
typedef __attribute__((ext_vector_type(8))) __bf16         bf16x8;
typedef __attribute__((ext_vector_type(4))) unsigned short ushort4_t;

// fp32 -> bf16 round-to-nearest-even
static __device__ __forceinline__ unsigned short f2bf(float f) {
    unsigned u = __builtin_bit_cast(unsigned, f);
    u += 0x7fffu + ((u >> 16) & 1u);
    return (unsigned short)(u >> 16);
}
static __device__ __forceinline__ float bf2f(unsigned short h) {
    unsigned u = ((unsigned)h) << 16;
    return __builtin_bit_cast(float, u);
}
static __device__ __forceinline__ f32x4 mfma16(short8 a, short8 b, f32x4 c) {
    return __builtin_amdgcn_mfma_f32_16x16x32_bf16(
        __builtin_bit_cast(bf16x8, a), __builtin_bit_cast(bf16x8, b), c, 0, 0, 0);
}

// ---------------------------------------------------------------------------
// cast_split: fp32 -> (bf16 hi, bf16 lo) elementwise. n4 = count/4.
// ---------------------------------------------------------------------------
__global__ __launch_bounds__(256)
void cast_split(const float* __restrict__ src, unsigned short* __restrict__ hi,
                unsigned short* __restrict__ lo, int n4) {
    int i = blockIdx.x * blockDim.x + threadIdx.x;
    const int stride = gridDim.x * blockDim.x;
    for (; i < n4; i += stride) {
        float4 v = reinterpret_cast<const float4*>(src)[i];
        float f0 = v.x, f1 = v.y, f2 = v.z, f3 = v.w;
        ushort4_t h, l;
        h[0] = f2bf(f0); l[0] = f2bf(f0 - bf2f(h[0]));
        h[1] = f2bf(f1); l[1] = f2bf(f1 - bf2f(h[1]));
        h[2] = f2bf(f2); l[2] = f2bf(f2 - bf2f(h[2]));
        h[3] = f2bf(f3); l[3] = f2bf(f3 - bf2f(h[3]));
        reinterpret_cast<ushort4_t*>(hi)[i] = h;
        reinterpret_cast<ushort4_t*>(lo)[i] = l;
    }
}

// ---------------------------------------------------------------------------
// cast_wT: W fp32 [K][N] -> Th, Tl bf16 [N][K] (transposed, k-contiguous).
// 32x32 tiles via LDS. grid = (N/32, K/32), block = 256.
// ---------------------------------------------------------------------------
__global__ __launch_bounds__(256)
void cast_wT(const float* __restrict__ W, unsigned short* __restrict__ Th,
             unsigned short* __restrict__ Tl, int K, int N) {
    __shared__ float Ls[32][36];              // pad 36 -> 16B-aligned rows
    const int tid = threadIdx.x;
    const int n0 = blockIdx.x * 32, k0 = blockIdx.y * 32;
    {
        const int row = tid >> 3, c4 = tid & 7;   // 256 thr = 32 rows x 8 float4
        float4 v = *reinterpret_cast<const float4*>(&W[(size_t)(k0 + row) * N + n0 + c4 * 4]);
        *reinterpret_cast<float4*>(&Ls[row][c4 * 4]) = v;
    }
    __syncthreads();
    {
        const int nl = tid >> 3, c4 = tid & 7;    // out row nl, k-chunk c4
        ushort4_t h, l;
#pragma unroll
        for (int j = 0; j < 4; ++j) {
            float f = Ls[c4 * 4 + j][nl];
            h[j] = f2bf(f);
            l[j] = f2bf(f - bf2f(h[j]));
        }
        const size_t o = (size_t)(n0 + nl) * K + k0 + c4 * 4;
        *reinterpret_cast<ushort4_t*>(&Th[o]) = h;
        *reinterpret_cast<ushort4_t*>(&Tl[o]) = l;
    }
}

// ---------------------------------------------------------------------------
// v_transpose: qkv(h,l) V-columns -> Vt(h,l) [bh][dk=64][T] (key-contiguous).
// grid = (T/64, B*NH), block = 256.
// ---------------------------------------------------------------------------
__global__ __launch_bounds__(256)
void v_transpose(const unsigned short* __restrict__ qh, const unsigned short* __restrict__ ql,
                 unsigned short* __restrict__ vth, unsigned short* __restrict__ vtl) {
    __shared__ unsigned short Ls[64][68];
    const int tt = blockIdx.x, bh = blockIdx.y;
    const int b = bh >> 4, h = bh & 15;
    const size_t src_base = ((size_t)b * TS + (size_t)tt * 64) * C3 + 2 * D_MODEL + h * DK;
    const size_t dst_base = (size_t)bh * DK * TS + (size_t)tt * 64;
#pragma unroll
    for (int pass = 0; pass < 2; ++pass) {
        const unsigned short* src = pass ? ql : qh;
        unsigned short* dst = pass ? vtl : vth;
        if (pass) __syncthreads();   // previous readers done before overwrite
        for (int c = threadIdx.x; c < 1024; c += 256) {
            const int t = c >> 4, c4 = c & 15;
            ushort4_t v = *reinterpret_cast<const ushort4_t*>(&src[src_base + (size_t)t * C3 + c4 * 4]);
            *reinterpret_cast<ushort4_t*>(&Ls[t][c4 * 4]) = v;
        }
        __syncthreads();
        for (int c = threadIdx.x; c < 1024; c += 256) {
            const int d = c >> 4, t4 = c & 15;
            ushort4_t o;
            o[0] = Ls[t4 * 4 + 0][d];
            o[1] = Ls[t4 * 4 + 1][d];
            o[2] = Ls[t4 * 4 + 2][d];
            o[3] = Ls[t4 * 4 + 3][d];
            *reinterpret_cast<ushort4_t*>(&dst[dst_base + (size_t)d * TS + t4 * 4]) = o;
        }
    }
}

// ---------------------------------------------------------------------------
// gemm_split: C = (Ah+Al) @ (Bh+Bl)^T + bias, 3-MFMA split-bf16 (~fp32 acc.)
// A*: [M][K] bf16 (row-major, k-contig). B*: [N][K] bf16 (k-contig).
// BF16OUT=1: write Ch/Cl bf16 planes; else write Cf fp32.
// 128x128 tile, BK=32, 4 waves (2x2), each 64x64 via 4x4 16x16x32 frags.
// LDS slot-XOR swizzle (16B slot s = (kb + (r>>1))&3) -> 2-way (free) reads.
// ---------------------------------------------------------------------------
template <int BF16OUT>
__global__ __launch_bounds__(256)
void gemm_split(const unsigned short* __restrict__ Ah_g, const unsigned short* __restrict__ Al_g,
                const unsigned short* __restrict__ Bh_g, const unsigned short* __restrict__ Bl_g,
                const float* __restrict__ bias,
                float* __restrict__ Cf, unsigned short* __restrict__ Ch,
                unsigned short* __restrict__ Cl,
                int M, int N, int K) {
    __shared__ unsigned short AhL[128 * 32];
    __shared__ unsigned short AlL[128 * 32];
    __shared__ unsigned short BhL[128 * 32];
    __shared__ unsigned short BlL[128 * 32];

    const int tid  = threadIdx.x;
    const int lane = tid & 63, wid = tid >> 6;
    const int wm = wid >> 1, wn = wid & 1;
    const int bm = blockIdx.y * 128, bn = blockIdx.x * 128;
    const int lr = lane & 15, kg = lane >> 4;

    f32x4 acc[4][4];
#pragma unroll
    for (int m = 0; m < 4; ++m)
#pragma unroll
        for (int n = 0; n < 4; ++n) acc[m][n] = (f32x4){0.f, 0.f, 0.f, 0.f};

    const int sr  = tid >> 1;          // staging row 0..127
    const int shb = tid & 1;           // which 32B half of the 64B row
    const size_t a_row = (size_t)(bm + sr) * K;
    const size_t b_row = (size_t)(bn + sr) * K;

    for (int k0 = 0; k0 < K; k0 += 32) {
        short8 va[2], vb[2], vc[2], vd[2];
        int slot[2];
#pragma unroll
        for (int i = 0; i < 2; ++i) {
            const int kb = 2 * shb + i;
            slot[i] = (kb + (sr >> 1)) & 3;
            const size_t go = k0 + kb * 8;
            va[i] = *reinterpret_cast<const short8*>(&Ah_g[a_row + go]);
            vb[i] = *reinterpret_cast<const short8*>(&Al_g[a_row + go]);
            vc[i] = *reinterpret_cast<const short8*>(&Bh_g[b_row + go]);
            vd[i] = *reinterpret_cast<const short8*>(&Bl_g[b_row + go]);
        }
        __syncthreads();               // previous iteration's readers done
#pragma unroll
        for (int i = 0; i < 2; ++i) {
            *reinterpret_cast<short8*>(&AhL[sr * 32 + slot[i] * 8]) = va[i];
            *reinterpret_cast<short8*>(&AlL[sr * 32 + slot[i] * 8]) = vb[i];
            *reinterpret_cast<short8*>(&BhL[sr * 32 + slot[i] * 8]) = vc[i];
            *reinterpret_cast<short8*>(&BlL[sr * 32 + slot[i] * 8]) = vd[i];
        }
        __syncthreads();               // tile visible

        short8 ah[4], al[4], bh[4], bl[4];
#pragma unroll
        for (int m = 0; m < 4; ++m) {
            const int r = wm * 64 + m * 16 + lr;
            const int s = (kg + (r >> 1)) & 3;
            ah[m] = *reinterpret_cast<const short8*>(&AhL[r * 32 + s * 8]);
            al[m] = *reinterpret_cast<const short8*>(&AlL[r * 32 + s * 8]);
        }
#pragma unroll
        for (int n = 0; n < 4; ++n) {
            const int r = wn * 64 + n * 16 + lr;
            const int s = (kg + (r >> 1)) & 3;
            bh[n] = *reinterpret_cast<const short8*>(&BhL[r * 32 + s * 8]);
            bl[n] = *reinterpret_cast<const short8*>(&BlL[r * 32 + s * 8]);
        }
#pragma unroll
        for (int m = 0; m < 4; ++m)
#pragma unroll
            for (int n = 0; n < 4; ++n) {
                acc[m][n] = mfma16(ah[m], bh[n], acc[m][n]);
                acc[m][n] = mfma16(ah[m], bl[n], acc[m][n]);
                acc[m][n] = mfma16(al[m], bh[n], acc[m][n]);
            }
    }

    const int og = lane >> 4, oc = lane & 15;
#pragma unroll
    for (int n = 0; n < 4; ++n) {
        const int gc = bn + wn * 64 + n * 16 + oc;
        const float bz = bias[gc];
#pragma unroll
        for (int m = 0; m < 4; ++m) {
            const int gr0 = bm + wm * 64 + m * 16 + og * 4;
#pragma unroll
            for (int rr = 0; rr < 4; ++rr) {
                const float v = acc[m][n][rr] + bz;
                const size_t idx = (size_t)(gr0 + rr) * N + gc;
                if (BF16OUT) {
                    const unsigned short hh = f2bf(v);
                    Ch[idx] = hh;
                    Cl[idx] = f2bf(v - bf2f(hh));
                } else {
                    Cf[idx] = v;
                }
            }
        }
    }
}

// ---------------------------------------------------------------------------
// attn_mfma: causal flash attention, bf16 MFMA, split-V PV.
// Block = 4 waves; wave w owns query rows [qb*64 + 16w, +16). Barrier-free:
// K/V fragments read straight from global (L2-resident per head), P does a
// per-wave LDS round-trip (C-frag layout -> A-frag layout).
// grid = (T/64, B*NH).
// ---------------------------------------------------------------------------
__global__ __launch_bounds__(256)
void attn_mfma(const unsigned short* __restrict__ qkvh,
               const unsigned short* __restrict__ vth, const unsigned short* __restrict__ vtl,
               unsigned short* __restrict__ yh, unsigned short* __restrict__ yl) {
    const int qb = blockIdx.x;                 // 0..31
    const int bh = blockIdx.y;                 // 0..63
    const int b = bh >> 4, h = bh & 15;
    const int tid = threadIdx.x, w = tid >> 6, lane = tid & 63;
    const int lr = lane & 15, lg = lane >> 4;

    __shared__ unsigned short Ps[4][16][68];   // per-wave P tile [q][key]

    // Q fragments (A-operand): row = lr, k = lg*8..+7 (+32 for kf=1)
    const size_t qrow = ((size_t)b * TS + qb * 64 + w * 16 + lr) * C3 + h * DK;
    short8 qf[2];
    qf[0] = *reinterpret_cast<const short8*>(&qkvh[qrow + lg * 8]);
    qf[1] = *reinterpret_cast<const short8*>(&qkvh[qrow + 32 + lg * 8]);

    f32x4 yacc[4];
#pragma unroll
    for (int nf = 0; nf < 4; ++nf) yacc[nf] = (f32x4){0.f, 0.f, 0.f, 0.f};
    float mrun[4], lrun[4];
#pragma unroll
    for (int rr = 0; rr < 4; ++rr) { mrun[rr] = -1e30f; lrun[rr] = 0.f; }

    const size_t kbase = (size_t)b * TS * C3 + D_MODEL + h * DK;
    const size_t vbase = (size_t)bh * DK * TS;

    for (int kt = 0; kt <= qb; ++kt) {
        // ---- S = Q K^T : 8 MFMAs -------------------------------------------
        f32x4 s[4];
#pragma unroll
        for (int nf = 0; nf < 4; ++nf) {
            const size_t krow = kbase + (size_t)(kt * 64 + nf * 16 + lr) * C3;
            short8 kf0 = *reinterpret_cast<const short8*>(&qkvh[krow + lg * 8]);
            short8 kf1 = *reinterpret_cast<const short8*>(&qkvh[krow + 32 + lg * 8]);
            s[nf] = (f32x4){0.f, 0.f, 0.f, 0.f};
            s[nf] = mfma16(qf[0], kf0, s[nf]);
            s[nf] = mfma16(qf[1], kf1, s[nf]);
        }
        // ---- scale + causal mask (diagonal tile only) ----------------------
#pragma unroll
        for (int nf = 0; nf < 4; ++nf) {
            s[nf] *= 0.125f;                   // 1/sqrt(64)
            if (kt == qb) {
                const int key = kt * 64 + nf * 16 + lr;
#pragma unroll
                for (int rr = 0; rr < 4; ++rr) {
                    const int q = qb * 64 + w * 16 + lg * 4 + rr;
                    if (key > q) s[nf][rr] = -1e30f;
                }
            }
        }
        // ---- online softmax (row-group = 16 contiguous lanes) --------------
        float scl[4];
#pragma unroll
        for (int rr = 0; rr < 4; ++rr) {
            float rm = fmaxf(fmaxf(s[0][rr], s[1][rr]), fmaxf(s[2][rr], s[3][rr]));
            rm = fmaxf(rm, __shfl_xor(rm, 1, 16));
            rm = fmaxf(rm, __shfl_xor(rm, 2, 16));
            rm = fmaxf(rm, __shfl_xor(rm, 4, 16));
            rm = fmaxf(rm, __shfl_xor(rm, 8, 16));
            const float mn = fmaxf(mrun[rr], rm);
            float rs = 0.f;
#pragma unroll
            for (int nf = 0; nf < 4; ++nf) {
                const float p = __expf(s[nf][rr] - mn);
                s[nf][rr] = p;
                rs += p;
            }
            rs += __shfl_xor(rs, 1, 16);
            rs += __shfl_xor(rs, 2, 16);
            rs += __shfl_xor(rs, 4, 16);
            rs += __shfl_xor(rs, 8, 16);
            scl[rr] = __expf(mrun[rr] - mn);
            lrun[rr] = lrun[rr] * scl[rr] + rs;
            mrun[rr] = mn;
        }
#pragma unroll
        for (int nf = 0; nf < 4; ++nf)
#pragma unroll
            for (int rr = 0; rr < 4; ++rr) yacc[nf][rr] *= scl[rr];
        // ---- P -> LDS (bf16), per-wave, no barrier needed ------------------
#pragma unroll
        for (int nf = 0; nf < 4; ++nf)
#pragma unroll
            for (int rr = 0; rr < 4; ++rr)
                Ps[w][lg * 4 + rr][nf * 16 + lr] = f2bf(s[nf][rr]);
        // ---- O += P V  (split V: 16 MFMAs) ---------------------------------
#pragma unroll
        for (int kf = 0; kf < 2; ++kf) {
            short4_t p0 = *reinterpret_cast<const short4_t*>(&Ps[w][lr][kf * 32 + lg * 8]);
            short4_t p1 = *reinterpret_cast<const short4_t*>(&Ps[w][lr][kf * 32 + lg * 8 + 4]);
            short8 pa = __builtin_shufflevector(p0, p1, 0, 1, 2, 3, 4, 5, 6, 7);
#pragma unroll
            for (int nf = 0; nf < 4; ++nf) {
                const size_t vrow = vbase + (size_t)(nf * 16 + lr) * TS + kt * 64 + kf * 32 + lg * 8;
                short8 vh = *reinterpret_cast<const short8*>(&vth[vrow]);
                short8 vl = *reinterpret_cast<const short8*>(&vtl[vrow]);
                yacc[nf] = mfma16(pa, vh, yacc[nf]);
                yacc[nf] = mfma16(pa, vl, yacc[nf]);
            }
        }
    }

    // ---- epilogue: y = acc / l, write bf16 hi/lo planes --------------------
    const size_t orow = ((size_t)b * TS + qb * 64 + w * 16 + lg * 4) * D_MODEL + h * DK;
#pragma unroll
    for (int rr = 0; rr < 4; ++rr) {
        const float inv = 1.f / lrun[rr];
#pragma unroll
        for (int nf = 0; nf < 4; ++nf) {
            const float v = yacc[nf][rr] * inv;
            const size_t idx = orow + (size_t)rr * D_MODEL + nf * 16 + lr;
            const unsigned short hh = f2bf(v);
            yh[idx] = hh;
            yl[idx] = f2bf(v - bf2f(hh));
        }
    }
}

// ---------------------------------------------------------------------------
extern "C" void kernel_launch(void* const* d_in, const int* in_sizes, int n_in,
                              void* d_out, int out_size, void* d_ws, size_t ws_size,
                              hipStream_t stream) {
    const float* x      = (const float*)d_in[0];   // [B,T,C]
    const float* W_qkv  = (const float*)d_in[1];   // [C,3C]
    const float* b_qkv  = (const float*)d_in[2];   // [3C]
    const float* W_proj = (const float*)d_in[3];   // [C,C]
    const float* b_proj = (const float*)d_in[4];   // [C]
    float* out = (float*)d_out;                    // [B,T,C]

    char* ws = (char*)d_ws;
    size_t off = 0;
    auto carve = [&](size_t elems) {
        unsigned short* p = (unsigned short*)(ws + off);
        off += elems * sizeof(unsigned short);
        return p;
    };
    unsigned short* xh   = carve((size_t)M_ROWS * D_MODEL);
    unsigned short* xl   = carve((size_t)M_ROWS * D_MODEL);
    unsigned short* wqh  = carve((size_t)C3 * D_MODEL);        // [3C][C] transposed
    unsigned short* wql  = carve((size_t)C3 * D_MODEL);
    unsigned short* wph  = carve((size_t)D_MODEL * D_MODEL);   // [C][C] transposed
    unsigned short* wpl  = carve((size_t)D_MODEL * D_MODEL);
    unsigned short* qkvh = carve((size_t)M_ROWS * C3);
    unsigned short* qkvl = carve((size_t)M_ROWS * C3);
    unsigned short* vth  = carve((size_t)BS * NH * DK * TS);
    unsigned short* vtl  = carve((size_t)BS * NH * DK * TS);
    unsigned short* yhh  = carve((size_t)M_ROWS * D_MODEL);
    unsigned short* yll  = carve((size_t)M_ROWS * D_MODEL);
    // total ~208 MB of d_ws, all fully rewritten each call

    // 1) split-cast activations and (transposed) weights
    cast_split<<<2048, 256, 0, stream>>>(x, xh, xl, M_ROWS * D_MODEL / 4);
    cast_wT<<<dim3(C3 / 32, D_MODEL / 32), 256, 0, stream>>>(W_qkv, wqh, wql, D_MODEL, C3);
    cast_wT<<<dim3(D_MODEL / 32, D_MODEL / 32), 256, 0, stream>>>(W_proj, wph, wpl, D_MODEL, D_MODEL);

    // 2) qkv = x @ W_qkv + b_qkv  (split-bf16, bf16 hi/lo output planes)
    gemm_split<1><<<dim3(C3 / 128, M_ROWS / 128), 256, 0, stream>>>(
        xh, xl, wqh, wql, b_qkv, nullptr, qkvh, qkvl, M_ROWS, C3, D_MODEL);

    // 3) V -> Vt [bh][dk][T] hi/lo for k-contiguous PV B-fragments
    v_transpose<<<dim3(TS / 64, BS * NH), 256, 0, stream>>>(qkvh, qkvl, vth, vtl);

    // 4) causal flash attention (bf16 MFMA), y in bf16 hi/lo planes
    attn_mfma<<<dim3(TS / 64, BS * NH), 256, 0, stream>>>(qkvh, vth, vtl, yhh, yll);

    // 5) out = y @ W_proj + b_proj (split-bf16, fp32 output)
    gemm_split<0><<<dim3(D_MODEL / 128, M_ROWS / 128), 256, 0, stream>>>(
        yhh, yll, wph, wpl, b_proj, out, nullptr, nullptr, M_ROWS, D_MODEL, D_MODEL);
}

// Round 3
// 493.293 us; speedup vs baseline: 5.4000x; 2.0779x over previous
//
#include <hip/hip_runtime.h>
#include <math.h>
#include <stdint.h>

#define D_MODEL 1024
#define NH      16
#define DK      64
#define BS      4
#define TS      2048
#define M_ROWS  (BS*TS)       // 8192
#define C3      (3*D_MODEL)   // 3072

typedef __attribute__((ext_vector_type(8))) short          short8;
typedef __attribute__((ext_vector_type(4))) float          f32x4;
typedef __attribute__((ext_vector_type(8))) __bf16         bf16x8;
typedef __attribute__((ext_vector_type(4))) unsigned short ushort4_t;

// fp32 -> bf16 round-to-nearest-even
static __device__ __forceinline__ unsigned short f2bf(float f) {
    unsigned u = __builtin_bit_cast(unsigned, f);
    u += 0x7fffu + ((u >> 16) & 1u);
    return (unsigned short)(u >> 16);
}
static __device__ __forceinline__ float bf2f(unsigned short h) {
    unsigned u = ((unsigned)h) << 16;
    return __builtin_bit_cast(float, u);
}
static __device__ __forceinline__ f32x4 mfma16(short8 a, short8 b, f32x4 c) {
    return __builtin_amdgcn_mfma_f32_16x16x32_bf16(
        __builtin_bit_cast(bf16x8, a), __builtin_bit_cast(bf16x8, b), c, 0, 0, 0);
}
// async global->LDS, 16B per lane; LDS dest = wave-uniform base + lane*16
static __device__ __forceinline__ void gll16(const void* g, void* l) {
    __builtin_amdgcn_global_load_lds(
        (const __attribute__((address_space(1))) void*)g,
        (__attribute__((address_space(3))) void*)l, 16, 0, 0);
}

// ---------------------------------------------------------------------------
// cast_split: fp32 -> (bf16 hi, bf16 lo) elementwise. n4 = count/4.
// ---------------------------------------------------------------------------
__global__ __launch_bounds__(256)
void cast_split(const float* __restrict__ src, unsigned short* __restrict__ hi,
                unsigned short* __restrict__ lo, int n4) {
    int i = blockIdx.x * blockDim.x + threadIdx.x;
    const int stride = gridDim.x * blockDim.x;
    for (; i < n4; i += stride) {
        float4 v = reinterpret_cast<const float4*>(src)[i];
        float f0 = v.x, f1 = v.y, f2 = v.z, f3 = v.w;
        ushort4_t h, l;
        h[0] = f2bf(f0); l[0] = f2bf(f0 - bf2f(h[0]));
        h[1] = f2bf(f1); l[1] = f2bf(f1 - bf2f(h[1]));
        h[2] = f2bf(f2); l[2] = f2bf(f2 - bf2f(h[2]));
        h[3] = f2bf(f3); l[3] = f2bf(f3 - bf2f(h[3]));
        reinterpret_cast<ushort4_t*>(hi)[i] = h;
        reinterpret_cast<ushort4_t*>(lo)[i] = l;
    }
}

// ---------------------------------------------------------------------------
// cast_wT: W fp32 [K][N] -> Th, Tl bf16 [N][K] (transposed, k-contiguous).
// ---------------------------------------------------------------------------
__global__ __launch_bounds__(256)
void cast_wT(const float* __restrict__ W, unsigned short* __restrict__ Th,
             unsigned short* __restrict__ Tl, int K, int N) {
    __shared__ float Ls[32][36];
    const int tid = threadIdx.x;
    const int n0 = blockIdx.x * 32, k0 = blockIdx.y * 32;
    {
        const int row = tid >> 3, c4 = tid & 7;
        float4 v = *reinterpret_cast<const float4*>(&W[(size_t)(k0 + row) * N + n0 + c4 * 4]);
        *reinterpret_cast<float4*>(&Ls[row][c4 * 4]) = v;
    }
    __syncthreads();
    {
        const int nl = tid >> 3, c4 = tid & 7;
        ushort4_t h, l;
#pragma unroll
        for (int j = 0; j < 4; ++j) {
            float f = Ls[c4 * 4 + j][nl];
            h[j] = f2bf(f);
            l[j] = f2bf(f - bf2f(h[j]));
        }
        const size_t o = (size_t)(n0 + nl) * K + k0 + c4 * 4;
        *reinterpret_cast<ushort4_t*>(&Th[o]) = h;
        *reinterpret_cast<ushort4_t*>(&Tl[o]) = l;
    }
}

// ---------------------------------------------------------------------------
// v_transpose: qkv(h,l) V-columns -> Vt(h,l) [bh][dk=64][T] (key-contiguous).
// ---------------------------------------------------------------------------
__global__ __launch_bounds__(256)
void v_transpose(const unsigned short* __restrict__ qh, const unsigned short* __restrict__ ql,
                 unsigned short* __restrict__ vth, unsigned short* __restrict__ vtl) {
    __shared__ unsigned short Ls[64][68];
    const int tt = blockIdx.x, bh = blockIdx.y;
    const int b = bh >> 4, h = bh & 15;
    const size_t src_base = ((size_t)b * TS + (size_t)tt * 64) * C3 + 2 * D_MODEL + h * DK;
    const size_t dst_base = (size_t)bh * DK * TS + (size_t)tt * 64;
#pragma unroll
    for (int pass = 0; pass < 2; ++pass) {
        const unsigned short* src = pass ? ql : qh;
        unsigned short* dst = pass ? vtl : vth;
        if (pass) __syncthreads();
        for (int c = threadIdx.x; c < 1024; c += 256) {
            const int t = c >> 4, c4 = c & 15;
            ushort4_t v = *reinterpret_cast<const ushort4_t*>(&src[src_base + (size_t)t * C3 + c4 * 4]);
            *reinterpret_cast<ushort4_t*>(&Ls[t][c4 * 4]) = v;
        }
        __syncthreads();
        for (int c = threadIdx.x; c < 1024; c += 256) {
            const int d = c >> 4, t4 = c & 15;
            ushort4_t o;
            o[0] = Ls[t4 * 4 + 0][d];
            o[1] = Ls[t4 * 4 + 1][d];
            o[2] = Ls[t4 * 4 + 2][d];
            o[3] = Ls[t4 * 4 + 3][d];
            *reinterpret_cast<ushort4_t*>(&dst[dst_base + (size_t)d * TS + t4 * 4]) = o;
        }
    }
}

// ---------------------------------------------------------------------------
// gemm_split: C = (Ah+Al) @ (Bh+Bl)^T + bias, 3-MFMA split-bf16.
// Staging now via global_load_lds (16B) with XOR source-swizzle:
//   LDS slot c of row r holds global k-octet (c ^ ((r>>1)&3));
//   reader of octet kg reads slot kg ^ ((r>>1)&3).
// ---------------------------------------------------------------------------
template <int BF16OUT>
__global__ __launch_bounds__(256)
void gemm_split(const unsigned short* __restrict__ Ah_g, const unsigned short* __restrict__ Al_g,
                const unsigned short* __restrict__ Bh_g, const unsigned short* __restrict__ Bl_g,
                const float* __restrict__ bias,
                float* __restrict__ Cf, unsigned short* __restrict__ Ch,
                unsigned short* __restrict__ Cl,
                int M, int N, int K) {
    __shared__ unsigned short AhL[128 * 32];
    __shared__ unsigned short AlL[128 * 32];
    __shared__ unsigned short BhL[128 * 32];
    __shared__ unsigned short BlL[128 * 32];

    const int tid  = threadIdx.x;
    const int lane = tid & 63, wid = tid >> 6;
    const int wm = wid >> 1, wn = wid & 1;
    const int bm = blockIdx.y * 128, bn = blockIdx.x * 128;
    const int lr = lane & 15, kg = lane >> 4;

    f32x4 acc[4][4];
#pragma unroll
    for (int m = 0; m < 4; ++m)
#pragma unroll
        for (int n = 0; n < 4; ++n) acc[m][n] = (f32x4){0.f, 0.f, 0.f, 0.f};

    for (int k0 = 0; k0 < K; k0 += 32) {
        __syncthreads();               // previous iteration's readers done
#pragma unroll
        for (int j = 0; j < 2; ++j) {
            const int si  = j * 256 + wid * 64 + lane;   // 16B slot 0..511
            const int row = si >> 2, cc = si & 3;
            const int sc  = cc ^ ((row >> 1) & 3);
            const int lo  = (j * 256 + wid * 64) * 8;    // shorts, wave-uniform
            const size_t ga = (size_t)(bm + row) * K + k0 + sc * 8;
            const size_t gb = (size_t)(bn + row) * K + k0 + sc * 8;
            gll16(&Ah_g[ga], &AhL[lo]);
            gll16(&Al_g[ga], &AlL[lo]);
            gll16(&Bh_g[gb], &BhL[lo]);
            gll16(&Bl_g[gb], &BlL[lo]);
        }
        __syncthreads();               // drains vmcnt -> tile visible

        short8 ah[4], al[4], bh[4], bl[4];
#pragma unroll
        for (int m = 0; m < 4; ++m) {
            const int r = wm * 64 + m * 16 + lr;
            const int s = kg ^ ((r >> 1) & 3);
            ah[m] = *reinterpret_cast<const short8*>(&AhL[r * 32 + s * 8]);
            al[m] = *reinterpret_cast<const short8*>(&AlL[r * 32 + s * 8]);
        }
#pragma unroll
        for (int n = 0; n < 4; ++n) {
            const int r = wn * 64 + n * 16 + lr;
            const int s = kg ^ ((r >> 1) & 3);
            bh[n] = *reinterpret_cast<const short8*>(&BhL[r * 32 + s * 8]);
            bl[n] = *reinterpret_cast<const short8*>(&BlL[r * 32 + s * 8]);
        }
#pragma unroll
        for (int m = 0; m < 4; ++m)
#pragma unroll
            for (int n = 0; n < 4; ++n) {
                acc[m][n] = mfma16(ah[m], bh[n], acc[m][n]);
                acc[m][n] = mfma16(ah[m], bl[n], acc[m][n]);
                acc[m][n] = mfma16(al[m], bh[n], acc[m][n]);
            }
    }

    const int og = lane >> 4, oc = lane & 15;
#pragma unroll
    for (int n = 0; n < 4; ++n) {
        const int gc = bn + wn * 64 + n * 16 + oc;
        const float bz = bias[gc];
#pragma unroll
        for (int m = 0; m < 4; ++m) {
            const int gr0 = bm + wm * 64 + m * 16 + og * 4;
#pragma unroll
            for (int rr = 0; rr < 4; ++rr) {
                const float v = acc[m][n][rr] + bz;
                const size_t idx = (size_t)(gr0 + rr) * N + gc;
                if (BF16OUT) {
                    const unsigned short hh = f2bf(v);
                    Ch[idx] = hh;
                    Cl[idx] = f2bf(v - bf2f(hh));
                } else {
                    Cf[idx] = v;
                }
            }
        }
    }
}

// ---------------------------------------------------------------------------
// attn_mfma: causal flash attention, bf16 MFMA, swapped operands.
// Block = 4 waves (256 thr); wave owns 64 q-rows; QBLK = 256.
// Block p handles q-tiles {p, 7-p}  -> exactly 36 kt-iters per block,
// grid = (4, 64) = 256 blocks = 1 block/CU, perfectly balanced.
// K/V tiles (64 keys x 64) LDS-staged, double-buffered, global_load_lds with
// pre-swizzled source (byte ^= ((row&7)<<4) family); one barrier per iter,
// prefetch of kt+1 issued right after it (2-phase pipeline).
// Swapped QK^T: s = mfma(K,Q) -> C col = q (lane-local q) => softmax reduce
// is 2 shfl_xor; P stored as [q][key] with b64 writes; PV = mfma(V^T, P).
// ---------------------------------------------------------------------------
__global__ __launch_bounds__(256, 1)
void attn_mfma(const unsigned short* __restrict__ qkvh,
               const unsigned short* __restrict__ vth, const unsigned short* __restrict__ vtl,
               unsigned short* __restrict__ yh, unsigned short* __restrict__ yl) {
    const int pr = blockIdx.x;                 // pair 0..3
    const int bh = blockIdx.y;                 // 0..63
    const int b = bh >> 4, h = bh & 15;
    const int tid = threadIdx.x, w = tid >> 6, lane = tid & 63;
    const int lr = lane & 15, lg = lane >> 4;

    __shared__ unsigned short Kt[2][64 * 64];  // [key][dk]   8KB each
    __shared__ unsigned short Vhs[2][64 * 64]; // [d][key]
    __shared__ unsigned short Vls[2][64 * 64];
    __shared__ unsigned short Ps[4][64 * 64];  // per-wave P [q][key], XOR-swz

    const size_t kbase  = (size_t)b * TS * C3 + D_MODEL + (size_t)h * DK;
    const size_t vbase  = (size_t)bh * DK * TS;
    const size_t qbase  = (size_t)b * TS * C3 + (size_t)h * DK;
    unsigned short* PsW = &Ps[w][0];

    const f32x4 fz = (f32x4){0.f, 0.f, 0.f, 0.f};

    for (int qi = 0; qi < 2; ++qi) {
        const int qt = qi ? (7 - pr) : pr;
        const int q0 = qt * 256;
        const int qwbase = q0 + w * 64;        // wave's first q-row

        // Q fragments (B-operand): col q = mf*16+lr, k = kf*32 + lg*8
        short8 qreg[4][2];
#pragma unroll
        for (int mf = 0; mf < 4; ++mf) {
            const size_t qrow = qbase + (size_t)(qwbase + mf * 16 + lr) * C3;
            qreg[mf][0] = *reinterpret_cast<const short8*>(&qkvh[qrow + lg * 8]);
            qreg[mf][1] = *reinterpret_cast<const short8*>(&qkvh[qrow + 32 + lg * 8]);
        }

        f32x4 yacc[4][4];                      // [df][qf], y^T frags
#pragma unroll
        for (int df = 0; df < 4; ++df)
#pragma unroll
            for (int qf = 0; qf < 4; ++qf) yacc[df][qf] = fz;
        float mrun[4], lrun[4];
#pragma unroll
        for (int qf = 0; qf < 4; ++qf) { mrun[qf] = -1e30f; lrun[qf] = 0.f; }

        const int nkt = 4 * qt + 4;
        int cur = 0;

        // stage tile kt into buffer buf (all 4 waves cooperate)
        auto stage = [&](int buf, int kt) {
#pragma unroll
            for (int j = 0; j < 2; ++j) {
                const int si  = j * 256 + w * 64 + lane;  // 16B slot 0..511
                const int row = si >> 3, cs = si & 7;
                const int sc  = cs ^ (row & 7);
                const int lo  = (j * 256 + w * 64) * 8;   // shorts, wave-uniform
                gll16(&qkvh[kbase + (size_t)(kt * 64 + row) * C3 + sc * 8], &Kt[buf][lo]);
                gll16(&vth[vbase + (size_t)row * TS + kt * 64 + sc * 8], &Vhs[buf][lo]);
                gll16(&vtl[vbase + (size_t)row * TS + kt * 64 + sc * 8], &Vls[buf][lo]);
            }
        };
        auto ldsf = [&](const unsigned short* Tt, int row, int kslot) -> short8 {
            return *reinterpret_cast<const short8*>(
                reinterpret_cast<const char*>(Tt) + row * 128 + (((kslot ^ (row & 7)) & 7) << 4));
        };

        stage(cur, 0);
        for (int kt = 0; kt < nkt; ++kt) {
            __syncthreads();                   // tile kt ready; prev readers done
            if (kt + 1 < nkt) stage(cur ^ 1, kt + 1);

            if (kt * 64 <= qwbase + 63) {      // wave-uniform: skip fully-masked tiles
                // ---- S^T = K Q : s[mf][nf], C col = q = mf*16+lr ----------
                f32x4 s[4][4];
#pragma unroll
                for (int nf = 0; nf < 4; ++nf) {
                    const int krow = nf * 16 + lr;
                    short8 ka0 = ldsf(Kt[cur], krow, lg);
                    short8 ka1 = ldsf(Kt[cur], krow, 4 + lg);
#pragma unroll
                    for (int mf = 0; mf < 4; ++mf)
                        s[mf][nf] = mfma16(ka1, qreg[mf][1], mfma16(ka0, qreg[mf][0], fz));
                }
                // ---- scale + causal mask ----------------------------------
#pragma unroll
                for (int mf = 0; mf < 4; ++mf)
#pragma unroll
                    for (int nf = 0; nf < 4; ++nf) s[mf][nf] *= 0.125f;
                if (kt * 64 + 63 > qwbase) {
#pragma unroll
                    for (int mf = 0; mf < 4; ++mf) {
                        const int q = qwbase + mf * 16 + lr;
#pragma unroll
                        for (int nf = 0; nf < 4; ++nf)
#pragma unroll
                            for (int rr = 0; rr < 4; ++rr)
                                if (kt * 64 + nf * 16 + lg * 4 + rr > q) s[mf][nf][rr] = -1e30f;
                    }
                }
                // ---- online softmax (q lane-local; reduce over lg: 2 shfl) -
                float sclv[4];
#pragma unroll
                for (int mf = 0; mf < 4; ++mf) {
                    float rm = s[mf][0][0];
#pragma unroll
                    for (int nf = 0; nf < 4; ++nf)
#pragma unroll
                        for (int rr = 0; rr < 4; ++rr) rm = fmaxf(rm, s[mf][nf][rr]);
                    rm = fmaxf(rm, __shfl_xor(rm, 16, 64));
                    rm = fmaxf(rm, __shfl_xor(rm, 32, 64));
                    const float mn = fmaxf(mrun[mf], rm);
                    float rs = 0.f;
#pragma unroll
                    for (int nf = 0; nf < 4; ++nf)
#pragma unroll
                        for (int rr = 0; rr < 4; ++rr) {
                            const float p = __expf(s[mf][nf][rr] - mn);
                            s[mf][nf][rr] = p;
                            rs += p;
                        }
                    rs += __shfl_xor(rs, 16, 64);
                    rs += __shfl_xor(rs, 32, 64);
                    sclv[mf] = __expf(mrun[mf] - mn);
                    lrun[mf] = lrun[mf] * sclv[mf] + rs;
                    mrun[mf] = mn;
                }
#pragma unroll
                for (int df = 0; df < 4; ++df)
#pragma unroll
                    for (int qf = 0; qf < 4; ++qf) yacc[df][qf] *= sclv[qf];
                // ---- P -> LDS [q][key], b64 writes, XOR-swz ---------------
#pragma unroll
                for (int mf = 0; mf < 4; ++mf) {
                    const int q = mf * 16 + lr;
#pragma unroll
                    for (int nf = 0; nf < 4; ++nf) {
                        ushort4_t pw;
                        pw[0] = f2bf(s[mf][nf][0]);
                        pw[1] = f2bf(s[mf][nf][1]);
                        pw[2] = f2bf(s[mf][nf][2]);
                        pw[3] = f2bf(s[mf][nf][3]);
                        *reinterpret_cast<ushort4_t*>(
                            reinterpret_cast<char*>(PsW) +
                            ((q * 128 + (nf * 16 + lg * 4) * 2) ^ ((q & 7) << 4))) = pw;
                    }
                }
                // ---- O^T += V^T P : yacc[df][qf] --------------------------
#pragma unroll
                for (int kf = 0; kf < 2; ++kf) {
                    short8 pb[4];
#pragma unroll
                    for (int qf = 0; qf < 4; ++qf) {
                        const int q = qf * 16 + lr;
                        pb[qf] = *reinterpret_cast<const short8*>(
                            reinterpret_cast<const char*>(PsW) +
                            q * 128 + ((((kf << 2) + lg) ^ (q & 7)) << 4));
                    }
#pragma unroll
                    for (int df = 0; df < 4; ++df) {
                        const int d = df * 16 + lr;
                        short8 va = ldsf(Vhs[cur], d, (kf << 2) + lg);
                        short8 vb = ldsf(Vls[cur], d, (kf << 2) + lg);
#pragma unroll
                        for (int qf = 0; qf < 4; ++qf) {
                            yacc[df][qf] = mfma16(va, pb[qf], yacc[df][qf]);
                            yacc[df][qf] = mfma16(vb, pb[qf], yacc[df][qf]);
                        }
                    }
                }
            }
            cur ^= 1;
        }

        // ---- epilogue: y[q][d] = yacc^T / l, bf16 hi/lo planes ------------
#pragma unroll
        for (int qf = 0; qf < 4; ++qf) {
            const float inv = 1.f / lrun[qf];
            const size_t ro = ((size_t)b * TS + (qwbase + qf * 16 + lr)) * D_MODEL + h * DK;
#pragma unroll
            for (int df = 0; df < 4; ++df) {
                ushort4_t oh, ol;
#pragma unroll
                for (int rr = 0; rr < 4; ++rr) {
                    const float v = yacc[df][qf][rr] * inv;
                    oh[rr] = f2bf(v);
                    ol[rr] = f2bf(v - bf2f(oh[rr]));
                }
                *reinterpret_cast<ushort4_t*>(&yh[ro + df * 16 + lg * 4]) = oh;
                *reinterpret_cast<ushort4_t*>(&yl[ro + df * 16 + lg * 4]) = ol;
            }
        }
    }
}

// ---------------------------------------------------------------------------
extern "C" void kernel_launch(void* const* d_in, const int* in_sizes, int n_in,
                              void* d_out, int out_size, void* d_ws, size_t ws_size,
                              hipStream_t stream) {
    const float* x      = (const float*)d_in[0];
    const float* W_qkv  = (const float*)d_in[1];
    const float* b_qkv  = (const float*)d_in[2];
    const float* W_proj = (const float*)d_in[3];
    const float* b_proj = (const float*)d_in[4];
    float* out = (float*)d_out;

    char* ws = (char*)d_ws;
    size_t off = 0;
    auto carve = [&](size_t elems) {
        unsigned short* p = (unsigned short*)(ws + off);
        off += elems * sizeof(unsigned short);
        return p;
    };
    unsigned short* xh   = carve((size_t)M_ROWS * D_MODEL);
    unsigned short* xl   = carve((size_t)M_ROWS * D_MODEL);
    unsigned short* wqh  = carve((size_t)C3 * D_MODEL);
    unsigned short* wql  = carve((size_t)C3 * D_MODEL);
    unsigned short* wph  = carve((size_t)D_MODEL * D_MODEL);
    unsigned short* wpl  = carve((size_t)D_MODEL * D_MODEL);
    unsigned short* qkvh = carve((size_t)M_ROWS * C3);
    unsigned short* qkvl = carve((size_t)M_ROWS * C3);
    unsigned short* vth  = carve((size_t)BS * NH * DK * TS);
    unsigned short* vtl  = carve((size_t)BS * NH * DK * TS);
    unsigned short* yhh  = carve((size_t)M_ROWS * D_MODEL);
    unsigned short* yll  = carve((size_t)M_ROWS * D_MODEL);

    cast_split<<<2048, 256, 0, stream>>>(x, xh, xl, M_ROWS * D_MODEL / 4);
    cast_wT<<<dim3(C3 / 32, D_MODEL / 32), 256, 0, stream>>>(W_qkv, wqh, wql, D_MODEL, C3);
    cast_wT<<<dim3(D_MODEL / 32, D_MODEL / 32), 256, 0, stream>>>(W_proj, wph, wpl, D_MODEL, D_MODEL);

    gemm_split<1><<<dim3(C3 / 128, M_ROWS / 128), 256, 0, stream>>>(
        xh, xl, wqh, wql, b_qkv, nullptr, qkvh, qkvl, M_ROWS, C3, D_MODEL);

    v_transpose<<<dim3(TS / 64, BS * NH), 256, 0, stream>>>(qkvh, qkvl, vth, vtl);

    attn_mfma<<<dim3(4, BS * NH), 256, 0, stream>>>(qkvh, vth, vtl, yhh, yll);

    gemm_split<0><<<dim3(D_MODEL / 128, M_ROWS / 128), 256, 0, stream>>>(
        yhh, yll, wph, wpl, b_proj, out, nullptr, nullptr, M_ROWS, D_MODEL, D_MODEL);
}

// Round 4
// 451.809 us; speedup vs baseline: 5.8958x; 1.0918x over previous
//
#include <hip/hip_runtime.h>
#include <math.h>
#include <stdint.h>

#define D_MODEL 1024
#define NH      16
#define DK      64
#define BS      4
#define TS      2048
#define M_ROWS  (BS*TS)       // 8192
#define C3      (3*D_MODEL)   // 3072

typedef __attribute__((ext_vector_type(8))) short          short8;
typedef __attribute__((ext_vector_type(4))) float          f32x4;
typedef __attribute__((ext_vector_type(8))) __bf16         bf16x8;
typedef __attribute__((ext_vector_type(4))) unsigned short ushort4_t;

// fp32 -> bf16 round-to-nearest-even
static __device__ __forceinline__ unsigned short f2bf(float f) {
    unsigned u = __builtin_bit_cast(unsigned, f);
    u += 0x7fffu + ((u >> 16) & 1u);
    return (unsigned short)(u >> 16);
}
static __device__ __forceinline__ float bf2f(unsigned short h) {
    unsigned u = ((unsigned)h) << 16;
    return __builtin_bit_cast(float, u);
}
static __device__ __forceinline__ f32x4 mfma16(short8 a, short8 b, f32x4 c) {
    return __builtin_amdgcn_mfma_f32_16x16x32_bf16(
        __builtin_bit_cast(bf16x8, a), __builtin_bit_cast(bf16x8, b), c, 0, 0, 0);
}
// async global->LDS, 16B per lane; LDS dest = wave-uniform base + lane*16
static __device__ __forceinline__ void gll16(const void* g, void* l) {
    __builtin_amdgcn_global_load_lds(
        (const __attribute__((address_space(1))) void*)g,
        (__attribute__((address_space(3))) void*)l, 16, 0, 0);
}

// ---------------------------------------------------------------------------
// cast_split: fp32 -> (bf16 hi, bf16 lo) elementwise. n4 = count/4.
// ---------------------------------------------------------------------------
__global__ __launch_bounds__(256)
void cast_split(const float* __restrict__ src, unsigned short* __restrict__ hi,
                unsigned short* __restrict__ lo, int n4) {
    int i = blockIdx.x * blockDim.x + threadIdx.x;
    const int stride = gridDim.x * blockDim.x;
    for (; i < n4; i += stride) {
        float4 v = reinterpret_cast<const float4*>(src)[i];
        float f0 = v.x, f1 = v.y, f2 = v.z, f3 = v.w;
        ushort4_t h, l;
        h[0] = f2bf(f0); l[0] = f2bf(f0 - bf2f(h[0]));
        h[1] = f2bf(f1); l[1] = f2bf(f1 - bf2f(h[1]));
        h[2] = f2bf(f2); l[2] = f2bf(f2 - bf2f(h[2]));
        h[3] = f2bf(f3); l[3] = f2bf(f3 - bf2f(h[3]));
        reinterpret_cast<ushort4_t*>(hi)[i] = h;
        reinterpret_cast<ushort4_t*>(lo)[i] = l;
    }
}

// ---------------------------------------------------------------------------
// cast_wT: W fp32 [K][N] -> Th, Tl bf16 [N][K] (transposed, k-contiguous).
// ---------------------------------------------------------------------------
__global__ __launch_bounds__(256)
void cast_wT(const float* __restrict__ W, unsigned short* __restrict__ Th,
             unsigned short* __restrict__ Tl, int K, int N) {
    __shared__ float Ls[32][36];
    const int tid = threadIdx.x;
    const int n0 = blockIdx.x * 32, k0 = blockIdx.y * 32;
    {
        const int row = tid >> 3, c4 = tid & 7;
        float4 v = *reinterpret_cast<const float4*>(&W[(size_t)(k0 + row) * N + n0 + c4 * 4]);
        *reinterpret_cast<float4*>(&Ls[row][c4 * 4]) = v;
    }
    __syncthreads();
    {
        const int nl = tid >> 3, c4 = tid & 7;
        ushort4_t h, l;
#pragma unroll
        for (int j = 0; j < 4; ++j) {
            float f = Ls[c4 * 4 + j][nl];
            h[j] = f2bf(f);
            l[j] = f2bf(f - bf2f(h[j]));
        }
        const size_t o = (size_t)(n0 + nl) * K + k0 + c4 * 4;
        *reinterpret_cast<ushort4_t*>(&Th[o]) = h;
        *reinterpret_cast<ushort4_t*>(&Tl[o]) = l;
    }
}

// ---------------------------------------------------------------------------
// v_transpose: qkv(h,l) V-columns -> Vt(h,l) [bh][dk=64][T] (key-contiguous).
// ---------------------------------------------------------------------------
__global__ __launch_bounds__(256)
void v_transpose(const unsigned short* __restrict__ qh, const unsigned short* __restrict__ ql,
                 unsigned short* __restrict__ vth, unsigned short* __restrict__ vtl) {
    __shared__ unsigned short Ls[64][68];
    const int tt = blockIdx.x, bh = blockIdx.y;
    const int b = bh >> 4, h = bh & 15;
    const size_t src_base = ((size_t)b * TS + (size_t)tt * 64) * C3 + 2 * D_MODEL + h * DK;
    const size_t dst_base = (size_t)bh * DK * TS + (size_t)tt * 64;
#pragma unroll
    for (int pass = 0; pass < 2; ++pass) {
        const unsigned short* src = pass ? ql : qh;
        unsigned short* dst = pass ? vtl : vth;
        if (pass) __syncthreads();
        for (int c = threadIdx.x; c < 1024; c += 256) {
            const int t = c >> 4, c4 = c & 15;
            ushort4_t v = *reinterpret_cast<const ushort4_t*>(&src[src_base + (size_t)t * C3 + c4 * 4]);
            *reinterpret_cast<ushort4_t*>(&Ls[t][c4 * 4]) = v;
        }
        __syncthreads();
        for (int c = threadIdx.x; c < 1024; c += 256) {
            const int d = c >> 4, t4 = c & 15;
            ushort4_t o;
            o[0] = Ls[t4 * 4 + 0][d];
            o[1] = Ls[t4 * 4 + 1][d];
            o[2] = Ls[t4 * 4 + 2][d];
            o[3] = Ls[t4 * 4 + 3][d];
            *reinterpret_cast<ushort4_t*>(&dst[dst_base + (size_t)d * TS + t4 * 4]) = o;
        }
    }
}

// ---------------------------------------------------------------------------
// gemm_split: C = (Ah+Al) @ (Bh+Bl)^T + bias, 3-MFMA split-bf16.
// (unchanged from round 3: ~860 TF effective, at the 2-barrier structure
//  ceiling; candidate for 8-phase 256^2 port in a later round)
// ---------------------------------------------------------------------------
template <int BF16OUT>
__global__ __launch_bounds__(256)
void gemm_split(const unsigned short* __restrict__ Ah_g, const unsigned short* __restrict__ Al_g,
                const unsigned short* __restrict__ Bh_g, const unsigned short* __restrict__ Bl_g,
                const float* __restrict__ bias,
                float* __restrict__ Cf, unsigned short* __restrict__ Ch,
                unsigned short* __restrict__ Cl,
                int M, int N, int K) {
    __shared__ unsigned short AhL[128 * 32];
    __shared__ unsigned short AlL[128 * 32];
    __shared__ unsigned short BhL[128 * 32];
    __shared__ unsigned short BlL[128 * 32];

    const int tid  = threadIdx.x;
    const int lane = tid & 63, wid = tid >> 6;
    const int wm = wid >> 1, wn = wid & 1;
    const int bm = blockIdx.y * 128, bn = blockIdx.x * 128;
    const int lr = lane & 15, kg = lane >> 4;

    f32x4 acc[4][4];
#pragma unroll
    for (int m = 0; m < 4; ++m)
#pragma unroll
        for (int n = 0; n < 4; ++n) acc[m][n] = (f32x4){0.f, 0.f, 0.f, 0.f};

    for (int k0 = 0; k0 < K; k0 += 32) {
        __syncthreads();               // previous iteration's readers done
#pragma unroll
        for (int j = 0; j < 2; ++j) {
            const int si  = j * 256 + wid * 64 + lane;   // 16B slot 0..511
            const int row = si >> 2, cc = si & 3;
            const int sc  = cc ^ ((row >> 1) & 3);
            const int lo  = (j * 256 + wid * 64) * 8;    // shorts, wave-uniform
            const size_t ga = (size_t)(bm + row) * K + k0 + sc * 8;
            const size_t gb = (size_t)(bn + row) * K + k0 + sc * 8;
            gll16(&Ah_g[ga], &AhL[lo]);
            gll16(&Al_g[ga], &AlL[lo]);
            gll16(&Bh_g[gb], &BhL[lo]);
            gll16(&Bl_g[gb], &BlL[lo]);
        }
        __syncthreads();               // drains vmcnt -> tile visible

        short8 ah[4], al[4], bh[4], bl[4];
#pragma unroll
        for (int m = 0; m < 4; ++m) {
            const int r = wm * 64 + m * 16 + lr;
            const int s = kg ^ ((r >> 1) & 3);
            ah[m] = *reinterpret_cast<const short8*>(&AhL[r * 32 + s * 8]);
            al[m] = *reinterpret_cast<const short8*>(&AlL[r * 32 + s * 8]);
        }
#pragma unroll
        for (int n = 0; n < 4; ++n) {
            const int r = wn * 64 + n * 16 + lr;
            const int s = kg ^ ((r >> 1) & 3);
            bh[n] = *reinterpret_cast<const short8*>(&BhL[r * 32 + s * 8]);
            bl[n] = *reinterpret_cast<const short8*>(&BlL[r * 32 + s * 8]);
        }
#pragma unroll
        for (int m = 0; m < 4; ++m)
#pragma unroll
            for (int n = 0; n < 4; ++n) {
                acc[m][n] = mfma16(ah[m], bh[n], acc[m][n]);
                acc[m][n] = mfma16(ah[m], bl[n], acc[m][n]);
                acc[m][n] = mfma16(al[m], bh[n], acc[m][n]);
            }
    }

    const int og = lane >> 4, oc = lane & 15;
#pragma unroll
    for (int n = 0; n < 4; ++n) {
        const int gc = bn + wn * 64 + n * 16 + oc;
        const float bz = bias[gc];
#pragma unroll
        for (int m = 0; m < 4; ++m) {
            const int gr0 = bm + wm * 64 + m * 16 + og * 4;
#pragma unroll
            for (int rr = 0; rr < 4; ++rr) {
                const float v = acc[m][n][rr] + bz;
                const size_t idx = (size_t)(gr0 + rr) * N + gc;
                if (BF16OUT) {
                    const unsigned short hh = f2bf(v);
                    Ch[idx] = hh;
                    Cl[idx] = f2bf(v - bf2f(hh));
                } else {
                    Cf[idx] = v;
                }
            }
        }
    }
}

// ---------------------------------------------------------------------------
// attn_mfma: causal flash attention, bf16 MFMA, swapped operands.
// ROUND 4: 8 waves x 32 q-rows (512 thr) instead of 4 x 64 -> 2 waves/SIMD
// so one wave's MFMA hides the other's softmax VALU (m114 co-schedule);
// s_setprio(1) around MFMA clusters (T5). QBLK=256, block p does q-tiles
// {p, 7-p} -> exactly 36 kt-iters/block, grid (4,64) = 256 = 1 block/CU.
// K/V tiles LDS-staged, double-buffered, global_load_lds with pre-swizzled
// source (byte ^= (row&7)<<4); one barrier per iter, prefetch kt+1 after it.
// Swapped QK^T: s = mfma(K,Q) -> q is lane-local => softmax reduce = 2 shfl.
// ---------------------------------------------------------------------------
__global__ __launch_bounds__(512, 2)
void attn_mfma(const unsigned short* __restrict__ qkvh,
               const unsigned short* __restrict__ vth, const unsigned short* __restrict__ vtl,
               unsigned short* __restrict__ yh, unsigned short* __restrict__ yl) {
    const int pr = blockIdx.x;                 // pair 0..3
    const int bh = blockIdx.y;                 // 0..63
    const int b = bh >> 4, h = bh & 15;
    const int tid = threadIdx.x, w = tid >> 6, lane = tid & 63;
    const int lr = lane & 15, lg = lane >> 4;

    __shared__ unsigned short Kt[2][64 * 64];  // [key][dk]   8KB each
    __shared__ unsigned short Vhs[2][64 * 64]; // [d][key]
    __shared__ unsigned short Vls[2][64 * 64];
    __shared__ unsigned short Ps[8][32 * 64];  // per-wave P [q][key], XOR-swz

    const size_t kbase  = (size_t)b * TS * C3 + D_MODEL + (size_t)h * DK;
    const size_t vbase  = (size_t)bh * DK * TS;
    const size_t qbase  = (size_t)b * TS * C3 + (size_t)h * DK;
    unsigned short* PsW = &Ps[w][0];

    const f32x4 fz = (f32x4){0.f, 0.f, 0.f, 0.f};

    // staging indices (512 threads: 1 gll16 per buffer per thread)
    const int srow = tid >> 3;                 // tile row 0..63
    const int ssc  = (tid & 7) ^ (srow & 7);   // swizzled 16B slot in row
    const int slds = (w * 64) * 8;             // wave-uniform LDS base (shorts)

    for (int qi = 0; qi < 2; ++qi) {
        const int qt = qi ? (7 - pr) : pr;
        const int q0 = qt * 256;
        const int qwbase = q0 + w * 32;        // wave's first q-row

        // Q fragments (B-operand): col q = mf*16+lr, k = kf*32 + lg*8
        short8 qreg[2][2];
#pragma unroll
        for (int mf = 0; mf < 2; ++mf) {
            const size_t qrow = qbase + (size_t)(qwbase + mf * 16 + lr) * C3;
            qreg[mf][0] = *reinterpret_cast<const short8*>(&qkvh[qrow + lg * 8]);
            qreg[mf][1] = *reinterpret_cast<const short8*>(&qkvh[qrow + 32 + lg * 8]);
        }

        f32x4 yacc[4][2];                      // [df][qf], y^T frags
#pragma unroll
        for (int df = 0; df < 4; ++df)
#pragma unroll
            for (int qf = 0; qf < 2; ++qf) yacc[df][qf] = fz;
        float mrun[2], lrun[2];
#pragma unroll
        for (int qf = 0; qf < 2; ++qf) { mrun[qf] = -1e30f; lrun[qf] = 0.f; }

        const int nkt = 4 * qt + 4;
        int cur = 0;

        auto stage = [&](int buf, int kt) {
            gll16(&qkvh[kbase + (size_t)(kt * 64 + srow) * C3 + ssc * 8], &Kt[buf][slds]);
            gll16(&vth[vbase + (size_t)srow * TS + kt * 64 + ssc * 8], &Vhs[buf][slds]);
            gll16(&vtl[vbase + (size_t)srow * TS + kt * 64 + ssc * 8], &Vls[buf][slds]);
        };
        auto ldsf = [&](const unsigned short* Tt, int row, int kslot) -> short8 {
            return *reinterpret_cast<const short8*>(
                reinterpret_cast<const char*>(Tt) + row * 128 + (((kslot ^ (row & 7)) & 7) << 4));
        };

        stage(cur, 0);
        for (int kt = 0; kt < nkt; ++kt) {
            __syncthreads();                   // tile kt ready; prev readers done
            if (kt + 1 < nkt) stage(cur ^ 1, kt + 1);

            if (kt * 64 <= qwbase + 31) {      // wave-uniform: skip fully-masked tiles
                // ---- S^T = K Q : s[mf][nf], C col = q = mf*16+lr ----------
                f32x4 s[2][4];
                __builtin_amdgcn_s_setprio(1);
#pragma unroll
                for (int nf = 0; nf < 4; ++nf) {
                    const int krow = nf * 16 + lr;
                    short8 ka0 = ldsf(Kt[cur], krow, lg);
                    short8 ka1 = ldsf(Kt[cur], krow, 4 + lg);
#pragma unroll
                    for (int mf = 0; mf < 2; ++mf)
                        s[mf][nf] = mfma16(ka1, qreg[mf][1], mfma16(ka0, qreg[mf][0], fz));
                }
                __builtin_amdgcn_s_setprio(0);
                // ---- scale + causal mask ----------------------------------
#pragma unroll
                for (int mf = 0; mf < 2; ++mf)
#pragma unroll
                    for (int nf = 0; nf < 4; ++nf) s[mf][nf] *= 0.125f;
                if (kt * 64 + 63 > qwbase) {
#pragma unroll
                    for (int mf = 0; mf < 2; ++mf) {
                        const int q = qwbase + mf * 16 + lr;
#pragma unroll
                        for (int nf = 0; nf < 4; ++nf)
#pragma unroll
                            for (int rr = 0; rr < 4; ++rr)
                                if (kt * 64 + nf * 16 + lg * 4 + rr > q) s[mf][nf][rr] = -1e30f;
                    }
                }
                // ---- online softmax (q lane-local; reduce over lg: 2 shfl) -
                float sclv[2];
#pragma unroll
                for (int mf = 0; mf < 2; ++mf) {
                    float rm = s[mf][0][0];
#pragma unroll
                    for (int nf = 0; nf < 4; ++nf)
#pragma unroll
                        for (int rr = 0; rr < 4; ++rr) rm = fmaxf(rm, s[mf][nf][rr]);
                    rm = fmaxf(rm, __shfl_xor(rm, 16, 64));
                    rm = fmaxf(rm, __shfl_xor(rm, 32, 64));
                    const float mn = fmaxf(mrun[mf], rm);
                    float rs = 0.f;
#pragma unroll
                    for (int nf = 0; nf < 4; ++nf)
#pragma unroll
                        for (int rr = 0; rr < 4; ++rr) {
                            const float p = __expf(s[mf][nf][rr] - mn);
                            s[mf][nf][rr] = p;
                            rs += p;
                        }
                    rs += __shfl_xor(rs, 16, 64);
                    rs += __shfl_xor(rs, 32, 64);
                    sclv[mf] = __expf(mrun[mf] - mn);
                    lrun[mf] = lrun[mf] * sclv[mf] + rs;
                    mrun[mf] = mn;
                }
#pragma unroll
                for (int df = 0; df < 4; ++df)
#pragma unroll
                    for (int qf = 0; qf < 2; ++qf) yacc[df][qf] *= sclv[qf];
                // ---- P -> LDS [q][key], b64 writes, XOR-swz ---------------
#pragma unroll
                for (int mf = 0; mf < 2; ++mf) {
                    const int q = mf * 16 + lr;
#pragma unroll
                    for (int nf = 0; nf < 4; ++nf) {
                        ushort4_t pw;
                        pw[0] = f2bf(s[mf][nf][0]);
                        pw[1] = f2bf(s[mf][nf][1]);
                        pw[2] = f2bf(s[mf][nf][2]);
                        pw[3] = f2bf(s[mf][nf][3]);
                        *reinterpret_cast<ushort4_t*>(
                            reinterpret_cast<char*>(PsW) +
                            ((q * 128 + (nf * 16 + lg * 4) * 2) ^ ((q & 7) << 4))) = pw;
                    }
                }
                // ---- O^T += V^T P : yacc[df][qf] --------------------------
#pragma unroll
                for (int kf = 0; kf < 2; ++kf) {
                    short8 pb[2];
#pragma unroll
                    for (int qf = 0; qf < 2; ++qf) {
                        const int q = qf * 16 + lr;
                        pb[qf] = *reinterpret_cast<const short8*>(
                            reinterpret_cast<const char*>(PsW) +
                            q * 128 + ((((kf << 2) + lg) ^ (q & 7)) << 4));
                    }
                    __builtin_amdgcn_s_setprio(1);
#pragma unroll
                    for (int df = 0; df < 4; ++df) {
                        const int d = df * 16 + lr;
                        short8 va = ldsf(Vhs[cur], d, (kf << 2) + lg);
                        short8 vb = ldsf(Vls[cur], d, (kf << 2) + lg);
#pragma unroll
                        for (int qf = 0; qf < 2; ++qf) {
                            yacc[df][qf] = mfma16(va, pb[qf], yacc[df][qf]);
                            yacc[df][qf] = mfma16(vb, pb[qf], yacc[df][qf]);
                        }
                    }
                    __builtin_amdgcn_s_setprio(0);
                }
            }
            cur ^= 1;
        }

        // ---- epilogue: y[q][d] = yacc^T / l, bf16 hi/lo planes ------------
#pragma unroll
        for (int qf = 0; qf < 2; ++qf) {
            const float inv = 1.f / lrun[qf];
            const size_t ro = ((size_t)b * TS + (qwbase + qf * 16 + lr)) * D_MODEL + h * DK;
#pragma unroll
            for (int df = 0; df < 4; ++df) {
                ushort4_t oh, ol;
#pragma unroll
                for (int rr = 0; rr < 4; ++rr) {
                    const float v = yacc[df][qf][rr] * inv;
                    oh[rr] = f2bf(v);
                    ol[rr] = f2bf(v - bf2f(oh[rr]));
                }
                *reinterpret_cast<ushort4_t*>(&yh[ro + df * 16 + lg * 4]) = oh;
                *reinterpret_cast<ushort4_t*>(&yl[ro + df * 16 + lg * 4]) = ol;
            }
        }
    }
}

// ---------------------------------------------------------------------------
extern "C" void kernel_launch(void* const* d_in, const int* in_sizes, int n_in,
                              void* d_out, int out_size, void* d_ws, size_t ws_size,
                              hipStream_t stream) {
    const float* x      = (const float*)d_in[0];
    const float* W_qkv  = (const float*)d_in[1];
    const float* b_qkv  = (const float*)d_in[2];
    const float* W_proj = (const float*)d_in[3];
    const float* b_proj = (const float*)d_in[4];
    float* out = (float*)d_out;

    char* ws = (char*)d_ws;
    size_t off = 0;
    auto carve = [&](size_t elems) {
        unsigned short* p = (unsigned short*)(ws + off);
        off += elems * sizeof(unsigned short);
        return p;
    };
    unsigned short* xh   = carve((size_t)M_ROWS * D_MODEL);
    unsigned short* xl   = carve((size_t)M_ROWS * D_MODEL);
    unsigned short* wqh  = carve((size_t)C3 * D_MODEL);
    unsigned short* wql  = carve((size_t)C3 * D_MODEL);
    unsigned short* wph  = carve((size_t)D_MODEL * D_MODEL);
    unsigned short* wpl  = carve((size_t)D_MODEL * D_MODEL);
    unsigned short* qkvh = carve((size_t)M_ROWS * C3);
    unsigned short* qkvl = carve((size_t)M_ROWS * C3);
    unsigned short* vth  = carve((size_t)BS * NH * DK * TS);
    unsigned short* vtl  = carve((size_t)BS * NH * DK * TS);
    unsigned short* yhh  = carve((size_t)M_ROWS * D_MODEL);
    unsigned short* yll  = carve((size_t)M_ROWS * D_MODEL);

    cast_split<<<2048, 256, 0, stream>>>(x, xh, xl, M_ROWS * D_MODEL / 4);
    cast_wT<<<dim3(C3 / 32, D_MODEL / 32), 256, 0, stream>>>(W_qkv, wqh, wql, D_MODEL, C3);
    cast_wT<<<dim3(D_MODEL / 32, D_MODEL / 32), 256, 0, stream>>>(W_proj, wph, wpl, D_MODEL, D_MODEL);

    gemm_split<1><<<dim3(C3 / 128, M_ROWS / 128), 256, 0, stream>>>(
        xh, xl, wqh, wql, b_qkv, nullptr, qkvh, qkvl, M_ROWS, C3, D_MODEL);

    v_transpose<<<dim3(TS / 64, BS * NH), 256, 0, stream>>>(qkvh, qkvl, vth, vtl);

    attn_mfma<<<dim3(4, BS * NH), 512, 0, stream>>>(qkvh, vth, vtl, yhh, yll);

    gemm_split<0><<<dim3(D_MODEL / 128, M_ROWS / 128), 256, 0, stream>>>(
        yhh, yll, wph, wpl, b_proj, out, nullptr, nullptr, M_ROWS, D_MODEL, D_MODEL);
}